// Round 6
// baseline (263.107 us; speedup 1.0000x reference)
//
#include <hip/hip_runtime.h>
#include <hip/hip_fp16.h>

#define NG 32
#define BATCH 4096

// level1: [33][33][32][16][32] f32 -> T1[(x*32+z)*1089 + a*33+b'][o] fp16
// level0: [33][33][64][16]     f32 -> T0[(p*1089 + a*33+b')*64 + h]  f32
static constexpr size_t T1H_BYTES = 17842176ull * 2;
static constexpr size_t T0F_BYTES = 1115136ull * 4;

__device__ __forceinline__ void interp1(float v, const float* sb, const float* sil,
                                        int& i, float& d) {
    float e = expf(-fabsf(v));
    float s = (v > 0.f) ? (1.f - 0.5f * e) : (0.5f * e);
    s *= (float)NG;
    int ii = (int)s;                       // trunc (s >= 0)
    ii = ii < 0 ? 0 : (ii > NG - 1 ? NG - 1 : ii);
    d = (v - sb[ii]) * sil[ii];
    i = ii;
}

// ---------------------------------------------------------------------------
// Kernel 1: transpose tables (one block per cell a*33+b').
// ---------------------------------------------------------------------------
__global__ __launch_bounds__(256) void k_transpose(
    const float* __restrict__ L1, const float* __restrict__ L0,
    __half* __restrict__ T1, float* __restrict__ T0)
{
    __shared__ __half hbuf[32 * 516];   // [o][xz] pad: 8B-aligned rows
    __shared__ float  fbuf[64 * 17];    // [h][p] pad
    const int cell = blockIdx.x;
    const int tid = threadIdx.x;

    const float4* L1v = reinterpret_cast<const float4*>(L1 + (size_t)cell * 16384);
#pragma unroll
    for (int k = 0; k < 16; ++k) {
        int v = tid + k * 256;
        int idx = v * 4;
        int o = idx >> 9, r = idx & 511;
        float4 f = L1v[v];
        *reinterpret_cast<__half2*>(&hbuf[o * 516 + r])     = __float22half2_rn(make_float2(f.x, f.y));
        *reinterpret_cast<__half2*>(&hbuf[o * 516 + r + 2]) = __float22half2_rn(make_float2(f.z, f.w));
    }
    const float* L0s = L0 + (size_t)cell * 1024;
#pragma unroll
    for (int k = 0; k < 4; ++k) {
        int t = tid + k * 256;
        int h = t >> 4, p = t & 15;
        fbuf[h * 17 + p] = L0s[t];
    }
    __syncthreads();

#pragma unroll
    for (int k = 0; k < 8; ++k) {
        int t = tid + k * 256;
        int xz = t >> 2, o0 = (t & 3) * 8;
        __half tmp[8];
#pragma unroll
        for (int j = 0; j < 8; ++j) tmp[j] = hbuf[(o0 + j) * 516 + xz];
        *reinterpret_cast<uint4*>(&T1[((size_t)xz * 1089 + cell) * 32 + o0]) =
            *reinterpret_cast<const uint4*>(tmp);
    }
#pragma unroll
    for (int k = 0; k < 4; ++k) {
        int t = tid + k * 256;
        int p = t >> 6, h = t & 63;
        T0[((size_t)p * 1089 + cell) * 64 + h] = fbuf[h * 17 + p];
    }
}

// ---------------------------------------------------------------------------
// Kernel 2: prep — per-b interp params + z0 + second-level params, written
// compact to ws; also zero-inits out (stream-ordered before k_main).
// ---------------------------------------------------------------------------
__global__ __launch_bounds__(256) void k_prep(
    const float* __restrict__ X, const float* __restrict__ T0,
    const float* __restrict__ borders, const float* __restrict__ invlen,
    int* __restrict__ i1x, float* __restrict__ wx0, float* __restrict__ wx1,
    int* __restrict__ j1z, float* __restrict__ wz0, float* __restrict__ wz1,
    float* __restrict__ out)
{
    __shared__ float sb[33], sil[32];
    __shared__ int   scell[16][4];
    __shared__ float ssw[4][16][4];
    __shared__ float sz0[4][64];

    const int tid = threadIdx.x;
    const int b0 = blockIdx.x * 4;

    if (tid < 33) sb[tid] = borders[tid];
    if (tid >= 64 && tid < 96) sil[tid - 64] = invlen[tid - 64];
    // zero out (131072 floats / 1024 blocks = 128 per block)
    if (tid >= 128) out[blockIdx.x * 128 + (tid - 128)] = 0.f;
    __syncthreads();

    if (tid < 64) {
        const int p = tid & 15, bl = tid >> 4;
        const int b = b0 + bl;
        float x1 = X[(2 * p) * BATCH + b];
        float x2 = X[(2 * p + 1) * BATCH + b];
        int i1, i2; float d1, d2;
        interp1(x1, sb, sil, i1, d1);
        interp1(x2, sb, sil, i2, d2);
        float w00 = (1.f - d1) * (1.f - d2);
        float w01 = (1.f - d1) * d2;
        float w10 = d1 * (1.f - d2);
        float w11 = d1 * d2;
        scell[p][bl] = i1 * 33 + i2;
        ssw[0][p][bl] = w00; ssw[1][p][bl] = w01; ssw[2][p][bl] = w10; ssw[3][p][bl] = w11;
        i1x[p * BATCH + b] = i1;
        wx0[p * BATCH + b] = w00;   // pairs corner i1
        wx1[p * BATCH + b] = w10;   // pairs corner i1+1
    }
    __syncthreads();

    {
        const int h = tid & 63, bl = tid >> 6;
        float acc = 0.f;
#pragma unroll 4
        for (int p = 0; p < 16; ++p) {
            int cell = scell[p][bl];
            unsigned basep = ((unsigned)p * 1089u + (unsigned)cell) * 64u + (unsigned)h;
            float t00 = T0[basep];
            float t01 = T0[basep + 64];
            float t10 = T0[basep + 33 * 64];
            float t11 = T0[basep + 34 * 64];
            acc += ssw[0][p][bl] * t00 + ssw[1][p][bl] * t01 + ssw[2][p][bl] * t10 + ssw[3][p][bl] * t11;
        }
        sz0[bl][h] = acc;
    }
    __syncthreads();

    if (tid < 128) {
        const int z = tid & 31, bl = tid >> 5;
        const int b = b0 + bl;
        float z1 = sz0[bl][2 * z];
        float z2 = sz0[bl][2 * z + 1];
        int j1, j2u; float dz1, dz2;
        interp1(z1, sb, sil, j1, dz1);
        interp1(z2, sb, sil, j2u, dz2);
        (void)j2u;
        j1z[z * BATCH + b] = j1;
        wz0[z * BATCH + b] = (1.f - dz1) * (1.f - dz2);  // corner j1
        wz1[z * BATCH + b] = dz1 * (1.f - dz2);          // corner j1+1
    }
}

// ---------------------------------------------------------------------------
// Kernel 3: main gather. Grid = (BATCH/4) x 8 x-groups; xg = bid & 7 aligns
// x-slab pairs with XCDs (bid%8 == XCD round-robin) so each XCD's T1 working
// set is 2 x-slabs = 4.46 MB ~ L2-resident. Partial sums combined via fp32
// atomics into out (zeroed by k_prep).
// Lane layout: lane = zs*8 + jc*4 + oh -> 8 lanes cover 128B contiguous.
// ---------------------------------------------------------------------------
__device__ __forceinline__ void accumh2(__half2 acc[4], uint4 u, __half2 c) {
    union { unsigned u32; __half2 h2; } cv;
    cv.u32 = u.x; acc[0] = __hfma2(c, cv.h2, acc[0]);
    cv.u32 = u.y; acc[1] = __hfma2(c, cv.h2, acc[1]);
    cv.u32 = u.z; acc[2] = __hfma2(c, cv.h2, acc[2]);
    cv.u32 = u.w; acc[3] = __hfma2(c, cv.h2, acc[3]);
}

__global__ __launch_bounds__(256, 4) void k_main(
    const __half* __restrict__ T1,
    const int* __restrict__ i1x, const float* __restrict__ wx0, const float* __restrict__ wx1,
    const int* __restrict__ j1z, const float* __restrict__ wz0, const float* __restrict__ wz1,
    float* __restrict__ out)
{
    __shared__ int   si1[2][4];
    __shared__ float sX0[2][4], sX1[2][4];
    __shared__ int   sj1[32][4];
    __shared__ float sZ[2][32][4];

    const int tid = threadIdx.x;
    const int xg = blockIdx.x & 7;          // x-group -> XCD
    const int b0 = (blockIdx.x >> 3) * 4;

    if (tid < 8) {
        int xi = tid >> 2, bl = tid & 3;
        int x = xg * 2 + xi;
        int idx = x * BATCH + b0 + bl;
        si1[xi][bl] = i1x[idx]; sX0[xi][bl] = wx0[idx]; sX1[xi][bl] = wx1[idx];
    }
    if (tid < 128) {
        int z = tid >> 2, bl = tid & 3;
        int idx = z * BATCH + b0 + bl;
        sj1[z][bl] = j1z[idx]; sZ[0][z][bl] = wz0[idx]; sZ[1][z][bl] = wz1[idx];
    }
    __syncthreads();

    const int lane = tid & 63, bl = tid >> 6;
    const int b = b0 + bl;
    const int oh = lane & 3;
    const int jc = (lane >> 2) & 1;
    const int zs = lane >> 3;
    const unsigned loff = (unsigned)(jc * 32 + oh * 8);

    __half2 acc2[4];
#pragma unroll
    for (int k = 0; k < 4; ++k) acc2[k] = __half2half2(__float2half(0.f));

#pragma unroll
    for (int xi = 0; xi < 2; ++xi) {
        const int x = xg * 2 + xi;
        const int cb = si1[xi][bl] * 33;
        const float X0 = sX0[xi][bl], X1 = sX1[xi][bl];
        const unsigned xzb = (unsigned)(x * 32 + zs * 4) * 1089u;
#pragma unroll
        for (int zi = 0; zi < 4; ++zi) {
            const int z = zs * 4 + zi;
            const unsigned cell = (unsigned)(cb + sj1[z][bl]);
            const float Zc = sZ[jc][z][bl];
            const unsigned base = (xzb + (unsigned)zi * 1089u + cell) * 32u + loff;
            uint4 u0 = *reinterpret_cast<const uint4*>(T1 + base);            // (i1,   j1+jc)
            uint4 u1 = *reinterpret_cast<const uint4*>(T1 + base + 33 * 32);  // (i1+1, j1+jc)
            const float c0 = X0 * Zc, c1 = X1 * Zc;
            accumh2(acc2, u0, __float2half2_rn(c0));
            accumh2(acc2, u1, __float2half2_rn(c1));
        }
    }

    float accf[8];
#pragma unroll
    for (int k = 0; k < 4; ++k) {
        float2 f = __half22float2(acc2[k]);
        accf[2 * k] = f.x; accf[2 * k + 1] = f.y;
    }
#pragma unroll
    for (int m = 4; m <= 32; m <<= 1) {
#pragma unroll
        for (int k = 0; k < 8; ++k) accf[k] += __shfl_xor(accf[k], m, 64);
    }
    if (lane < 4) {
#pragma unroll
        for (int k = 0; k < 8; ++k)
            unsafeAtomicAdd(&out[(oh * 8 + k) * BATCH + b], accf[k]);
    }
}

extern "C" void kernel_launch(void* const* d_in, const int* in_sizes, int n_in,
                              void* d_out, int out_size, void* d_ws, size_t ws_size,
                              hipStream_t stream) {
    const float* X       = (const float*)d_in[0];
    const float* L0      = (const float*)d_in[1];
    const float* L1      = (const float*)d_in[2];
    const float* borders = (const float*)d_in[3];
    const float* invlen  = (const float*)d_in[4];
    float* out = (float*)d_out;

    char* ws = (char*)d_ws;
    __half* T1h = (__half*)ws;
    float*  T0f = (float*)(ws + T1H_BYTES);
    char* p = ws + T1H_BYTES + T0F_BYTES;
    int*   i1x = (int*)p;            p += 16 * BATCH * 4;
    float* wx0 = (float*)p;          p += 16 * BATCH * 4;
    float* wx1 = (float*)p;          p += 16 * BATCH * 4;
    int*   j1z = (int*)p;            p += 32 * BATCH * 4;
    float* wz0 = (float*)p;          p += 32 * BATCH * 4;
    float* wz1 = (float*)p;          p += 32 * BATCH * 4;

    hipLaunchKernelGGL(k_transpose, dim3(1089), dim3(256), 0, stream, L1, L0, T1h, T0f);
    hipLaunchKernelGGL(k_prep, dim3(BATCH / 4), dim3(256), 0, stream,
                       X, T0f, borders, invlen, i1x, wx0, wx1, j1z, wz0, wz1, out);
    hipLaunchKernelGGL(k_main, dim3((BATCH / 4) * 8), dim3(256), 0, stream,
                       T1h, i1x, wx0, wx1, j1z, wz0, wz1, out);
}

// Round 7
// 163.265 us; speedup vs baseline: 1.6115x; 1.6115x over previous
//
#include <hip/hip_runtime.h>
#include <hip/hip_fp16.h>

#define NG 32
#define BATCH 4096

// level1: [33][33][32][16][32] f32 -> T1[(x*32+z)*1089 + a*33+b'][o] fp16
// level0: [33][33][64][16]     f32 -> T0[(p*1089 + a*33+b')*64 + h]  f32
static constexpr size_t T1H_BYTES = 17842176ull * 2;
static constexpr size_t T0F_BYTES = 1115136ull * 4;

__device__ __forceinline__ void interp1(float v, const float* sb, const float* sil,
                                        int& i, float& d) {
    float e = expf(-fabsf(v));
    float s = (v > 0.f) ? (1.f - 0.5f * e) : (0.5f * e);
    s *= (float)NG;
    int ii = (int)s;                       // trunc (s >= 0)
    ii = ii < 0 ? 0 : (ii > NG - 1 ? NG - 1 : ii);
    d = (v - sb[ii]) * sil[ii];
    i = ii;
}

// ---------------------------------------------------------------------------
// Kernel 1: transpose tables (one block per cell a*33+b').
// ---------------------------------------------------------------------------
__global__ __launch_bounds__(256) void k_transpose(
    const float* __restrict__ L1, const float* __restrict__ L0,
    __half* __restrict__ T1, float* __restrict__ T0)
{
    __shared__ __half hbuf[32 * 516];   // [o][xz] pad: 8B-aligned rows
    __shared__ float  fbuf[64 * 17];    // [h][p] pad
    const int cell = blockIdx.x;
    const int tid = threadIdx.x;

    const float4* L1v = reinterpret_cast<const float4*>(L1 + (size_t)cell * 16384);
#pragma unroll
    for (int k = 0; k < 16; ++k) {
        int v = tid + k * 256;
        int idx = v * 4;
        int o = idx >> 9, r = idx & 511;
        float4 f = L1v[v];
        *reinterpret_cast<__half2*>(&hbuf[o * 516 + r])     = __float22half2_rn(make_float2(f.x, f.y));
        *reinterpret_cast<__half2*>(&hbuf[o * 516 + r + 2]) = __float22half2_rn(make_float2(f.z, f.w));
    }
    const float* L0s = L0 + (size_t)cell * 1024;
#pragma unroll
    for (int k = 0; k < 4; ++k) {
        int t = tid + k * 256;
        int h = t >> 4, p = t & 15;
        fbuf[h * 17 + p] = L0s[t];
    }
    __syncthreads();

#pragma unroll
    for (int k = 0; k < 8; ++k) {
        int t = tid + k * 256;
        int xz = t >> 2, o0 = (t & 3) * 8;
        __half tmp[8];
#pragma unroll
        for (int j = 0; j < 8; ++j) tmp[j] = hbuf[(o0 + j) * 516 + xz];
        *reinterpret_cast<uint4*>(&T1[((size_t)xz * 1089 + cell) * 32 + o0]) =
            *reinterpret_cast<const uint4*>(tmp);
    }
#pragma unroll
    for (int k = 0; k < 4; ++k) {
        int t = tid + k * 256;
        int p = t >> 6, h = t & 63;
        T0[((size_t)p * 1089 + cell) * 64 + h] = fbuf[h * 17 + p];
    }
}

// ---------------------------------------------------------------------------
// Kernel 2: prep — per-b interp params + z0 + second-level params (compact).
// ---------------------------------------------------------------------------
__global__ __launch_bounds__(256) void k_prep(
    const float* __restrict__ X, const float* __restrict__ T0,
    const float* __restrict__ borders, const float* __restrict__ invlen,
    int* __restrict__ i1x, float* __restrict__ wx0, float* __restrict__ wx1,
    int* __restrict__ j1z, float* __restrict__ wz0, float* __restrict__ wz1)
{
    __shared__ float sb[33], sil[32];
    __shared__ int   scell[16][4];
    __shared__ float ssw[4][16][4];
    __shared__ float sz0[4][64];

    const int tid = threadIdx.x;
    const int b0 = blockIdx.x * 4;

    if (tid < 33) sb[tid] = borders[tid];
    if (tid >= 64 && tid < 96) sil[tid - 64] = invlen[tid - 64];
    __syncthreads();

    if (tid < 64) {
        const int p = tid & 15, bl = tid >> 4;
        const int b = b0 + bl;
        float x1 = X[(2 * p) * BATCH + b];
        float x2 = X[(2 * p + 1) * BATCH + b];
        int i1, i2; float d1, d2;
        interp1(x1, sb, sil, i1, d1);
        interp1(x2, sb, sil, i2, d2);
        float w00 = (1.f - d1) * (1.f - d2);
        float w01 = (1.f - d1) * d2;
        float w10 = d1 * (1.f - d2);
        float w11 = d1 * d2;
        scell[p][bl] = i1 * 33 + i2;
        ssw[0][p][bl] = w00; ssw[1][p][bl] = w01; ssw[2][p][bl] = w10; ssw[3][p][bl] = w11;
        i1x[p * BATCH + b] = i1;
        wx0[p * BATCH + b] = w00;   // pairs corner i1
        wx1[p * BATCH + b] = w10;   // pairs corner i1+1
    }
    __syncthreads();

    {
        const int h = tid & 63, bl = tid >> 6;
        float acc = 0.f;
#pragma unroll 4
        for (int p = 0; p < 16; ++p) {
            int cell = scell[p][bl];
            unsigned basep = ((unsigned)p * 1089u + (unsigned)cell) * 64u + (unsigned)h;
            float t00 = T0[basep];
            float t01 = T0[basep + 64];
            float t10 = T0[basep + 33 * 64];
            float t11 = T0[basep + 34 * 64];
            acc += ssw[0][p][bl] * t00 + ssw[1][p][bl] * t01 + ssw[2][p][bl] * t10 + ssw[3][p][bl] * t11;
        }
        sz0[bl][h] = acc;
    }
    __syncthreads();

    if (tid < 128) {
        const int z = tid & 31, bl = tid >> 5;
        const int b = b0 + bl;
        float z1 = sz0[bl][2 * z];
        float z2 = sz0[bl][2 * z + 1];
        int j1, j2u; float dz1, dz2;
        interp1(z1, sb, sil, j1, dz1);
        interp1(z2, sb, sil, j2u, dz2);
        (void)j2u;
        j1z[z * BATCH + b] = j1;
        wz0[z * BATCH + b] = (1.f - dz1) * (1.f - dz2);  // corner j1
        wz1[z * BATCH + b] = dz1 * (1.f - dz2);          // corner j1+1
    }
}

// ---------------------------------------------------------------------------
// Kernel 3: main gather. Grid = 8 x-groups x (BATCH/4); xg = bid & 7 rides
// the round-robin block->XCD mapping so each XCD's T1 working set is 2
// x-slabs = 4.46 MB ~ L2-resident. NO atomics: each xg writes a private
// partial buffer part[xg][32][4096] (reuses dead T0F region of ws).
// Lane layout: lane = zs*8 + jc*4 + oh -> 8 lanes cover 128B contiguous.
// ---------------------------------------------------------------------------
__device__ __forceinline__ void accumh2(__half2 acc[4], uint4 u, __half2 c) {
    union { unsigned u32; __half2 h2; } cv;
    cv.u32 = u.x; acc[0] = __hfma2(c, cv.h2, acc[0]);
    cv.u32 = u.y; acc[1] = __hfma2(c, cv.h2, acc[1]);
    cv.u32 = u.z; acc[2] = __hfma2(c, cv.h2, acc[2]);
    cv.u32 = u.w; acc[3] = __hfma2(c, cv.h2, acc[3]);
}

__global__ __launch_bounds__(256, 8) void k_main(
    const __half* __restrict__ T1,
    const int* __restrict__ i1x, const float* __restrict__ wx0, const float* __restrict__ wx1,
    const int* __restrict__ j1z, const float* __restrict__ wz0, const float* __restrict__ wz1,
    float* __restrict__ part)
{
    __shared__ int   si1[2][4];
    __shared__ float sX0[2][4], sX1[2][4];
    __shared__ int   sj1[32][4];
    __shared__ float sZ[2][32][4];

    const int tid = threadIdx.x;
    const int xg = blockIdx.x & 7;          // x-group -> XCD
    const int b0 = (blockIdx.x >> 3) * 4;

    if (tid < 8) {
        int xi = tid >> 2, bl = tid & 3;
        int x = xg * 2 + xi;
        int idx = x * BATCH + b0 + bl;
        si1[xi][bl] = i1x[idx]; sX0[xi][bl] = wx0[idx]; sX1[xi][bl] = wx1[idx];
    }
    if (tid < 128) {
        int z = tid >> 2, bl = tid & 3;
        int idx = z * BATCH + b0 + bl;
        sj1[z][bl] = j1z[idx]; sZ[0][z][bl] = wz0[idx]; sZ[1][z][bl] = wz1[idx];
    }
    __syncthreads();

    const int lane = tid & 63, bl = tid >> 6;
    const int b = b0 + bl;
    const int oh = lane & 3;
    const int jc = (lane >> 2) & 1;
    const int zs = lane >> 3;
    const unsigned loff = (unsigned)(jc * 32 + oh * 8);

    __half2 acc2[4];
#pragma unroll
    for (int k = 0; k < 4; ++k) acc2[k] = __half2half2(__float2half(0.f));

#pragma unroll
    for (int xi = 0; xi < 2; ++xi) {
        const int x = xg * 2 + xi;
        const int cb = si1[xi][bl] * 33;
        const float X0 = sX0[xi][bl], X1 = sX1[xi][bl];
        const unsigned xzb = (unsigned)(x * 32 + zs * 4) * 1089u;
#pragma unroll
        for (int zi = 0; zi < 4; ++zi) {
            const int z = zs * 4 + zi;
            const unsigned cell = (unsigned)(cb + sj1[z][bl]);
            const float Zc = sZ[jc][z][bl];
            const unsigned base = (xzb + (unsigned)zi * 1089u + cell) * 32u + loff;
            uint4 u0 = *reinterpret_cast<const uint4*>(T1 + base);            // (i1,   j1+jc)
            uint4 u1 = *reinterpret_cast<const uint4*>(T1 + base + 33 * 32);  // (i1+1, j1+jc)
            const float c0 = X0 * Zc, c1 = X1 * Zc;
            accumh2(acc2, u0, __float2half2_rn(c0));
            accumh2(acc2, u1, __float2half2_rn(c1));
        }
    }

    float accf[8];
#pragma unroll
    for (int k = 0; k < 4; ++k) {
        float2 f = __half22float2(acc2[k]);
        accf[2 * k] = f.x; accf[2 * k + 1] = f.y;
    }
#pragma unroll
    for (int m = 4; m <= 32; m <<= 1) {
#pragma unroll
        for (int k = 0; k < 8; ++k) accf[k] += __shfl_xor(accf[k], m, 64);
    }
    if (lane < 4) {
#pragma unroll
        for (int k = 0; k < 8; ++k)
            part[(size_t)xg * (32 * BATCH) + (oh * 8 + k) * BATCH + b] = accf[k];
    }
}

// ---------------------------------------------------------------------------
// Kernel 4: reduce 8 partials -> out. 32768 float4 elems.
// ---------------------------------------------------------------------------
__global__ __launch_bounds__(256) void k_reduce(
    const float* __restrict__ part, float* __restrict__ out)
{
    const int i = blockIdx.x * 256 + threadIdx.x;   // float4 index, grid covers 32768
    const float4* p4 = reinterpret_cast<const float4*>(part);
    float4 s = p4[i];
#pragma unroll
    for (int g = 1; g < 8; ++g) {
        float4 t = p4[g * 32768 + i];
        s.x += t.x; s.y += t.y; s.z += t.z; s.w += t.w;
    }
    reinterpret_cast<float4*>(out)[i] = s;
}

extern "C" void kernel_launch(void* const* d_in, const int* in_sizes, int n_in,
                              void* d_out, int out_size, void* d_ws, size_t ws_size,
                              hipStream_t stream) {
    const float* X       = (const float*)d_in[0];
    const float* L0      = (const float*)d_in[1];
    const float* L1      = (const float*)d_in[2];
    const float* borders = (const float*)d_in[3];
    const float* invlen  = (const float*)d_in[4];
    float* out = (float*)d_out;

    char* ws = (char*)d_ws;
    __half* T1h = (__half*)ws;
    float*  T0f = (float*)(ws + T1H_BYTES);        // dead after k_prep
    float*  part = T0f;                            // reused: 8*32*4096*4 = 4 MB < T0F_BYTES
    char* p = ws + T1H_BYTES + T0F_BYTES;
    int*   i1x = (int*)p;            p += 16 * BATCH * 4;
    float* wx0 = (float*)p;          p += 16 * BATCH * 4;
    float* wx1 = (float*)p;          p += 16 * BATCH * 4;
    int*   j1z = (int*)p;            p += 32 * BATCH * 4;
    float* wz0 = (float*)p;          p += 32 * BATCH * 4;
    float* wz1 = (float*)p;          p += 32 * BATCH * 4;

    hipLaunchKernelGGL(k_transpose, dim3(1089), dim3(256), 0, stream, L1, L0, T1h, T0f);
    hipLaunchKernelGGL(k_prep, dim3(BATCH / 4), dim3(256), 0, stream,
                       X, T0f, borders, invlen, i1x, wx0, wx1, j1z, wz0, wz1);
    hipLaunchKernelGGL(k_main, dim3((BATCH / 4) * 8), dim3(256), 0, stream,
                       T1h, i1x, wx0, wx1, j1z, wz0, wz1, part);
    hipLaunchKernelGGL(k_reduce, dim3(32768 / 256), dim3(256), 0, stream, part, out);
}